// Round 1
// 320.197 us; speedup vs baseline: 2.0144x; 2.0144x over previous
//
#include <hip/hip_runtime.h>
#include <math.h>

// XMIX mixing network — split-bf16 MFMA rewrite.
// B = 32768 samples, TB = 64 samples/block, 512 blocks x 512 threads (8 waves).
// All GEMMs on v_mfma_f32_16x16x32_bf16 with hi/lo bf16 split (fp32-accurate:
// x = xh + xl, x*w ~= xh*wh + xh*wl + xl*wh, rel err ~2^-16).
// Weights pre-split+transposed into d_ws (needs 1,622,016 bytes).

#define NB 32768
#define TB 64
#define THREADS 512
#define NBLOCKS (NB / TB)   // 512

typedef short sh8 __attribute__((ext_vector_type(8)));  // 8 bf16 (4 VGPR)
typedef float f4 __attribute__((ext_vector_type(4)));   // MFMA C/D

// ---- workspace layout (ushort units). WT[col][k] hi/lo planes ----
#define OFF_WCAT_H 0                       // [640][512]  (W1a|Wfa|Wb1|Wv1|pad)
#define OFF_WCAT_L (640 * 512)
#define OFF_W1B_H  (2 * 640 * 512)        // [256][256]
#define OFF_W1B_L  (OFF_W1B_H + 256 * 256)
#define OFF_WFB_H  (OFF_W1B_L + 256 * 256) // [32][256]
#define OFF_WFB_L  (OFF_WFB_H + 32 * 256)
#define OFF_TOK_H  (OFF_WFB_L + 32 * 256)  // [32][64]
#define OFF_TOK_L  (OFF_TOK_H + 32 * 64)
#define OFF_YFC_H  (OFF_TOK_L + 32 * 64)   // [64][32]
#define OFF_YFC_L  (OFF_YFC_H + 64 * 32)
// total shorts = OFF_YFC_L + 64*32 = 811008  (1.62 MB of d_ws)

__device__ __forceinline__ unsigned short f2bf(float x) {
    unsigned u = __float_as_uint(x);
    u += 0x7fffu + ((u >> 16) & 1u);        // RNE
    return (unsigned short)(u >> 16);
}
__device__ __forceinline__ float bf2f(unsigned short h) {
    return __uint_as_float(((unsigned)h) << 16);
}
__device__ __forceinline__ void splitbf(float x, unsigned short& h, unsigned short& l) {
    h = f2bf(x);
    l = f2bf(x - bf2f(h));
}
__device__ __forceinline__ f4 mfma(sh8 a, sh8 b, f4 c) {
    return __builtin_amdgcn_mfma_f32_16x16x32_bf16(a, b, c, 0, 0, 0);
}

// LDS swizzles (bank-conflict fix for ds_read_b128 at power-of-2 row strides).
// Applied identically on write and read -> any bijection is self-consistent.
__device__ __forceinline__ unsigned swY(unsigned a) {   // 1024B-stride planes
    return a ^ (((((a >> 10) & 7) ^ ((a >> 7) & 7)) << 4));
}
__device__ __forceinline__ unsigned swH(unsigned a) {   // 512B-stride planes
    return a ^ (((a >> 9) & 7) << 4);
}
__device__ __forceinline__ unsigned swS(unsigned a) {   // 64B-stride scratch
    return a ^ (((a >> 7) & 3) << 4);
}

// ---------------- weight prep: split fp32 -> (hi,lo) bf16, transposed ----------------
__global__ void xmix_prep(
    const float* __restrict__ W_tok, const float* __restrict__ W_yfc,
    const float* __restrict__ W1a, const float* __restrict__ W1b,
    const float* __restrict__ Wfa, const float* __restrict__ Wfb,
    const float* __restrict__ Wb1, const float* __restrict__ Wv1,
    unsigned short* __restrict__ ws)
{
    const int stride = gridDim.x * blockDim.x;
    const int tid0 = blockIdx.x * blockDim.x + threadIdx.x;
    for (int i = tid0; i < 640 * 512; i += stride) {
        const int col = i >> 9, k = i & 511;
        float v = 0.f;
        if (col < 256) v = W1a[k * 256 + col];
        else if (col < 512) v = Wfa[k * 256 + (col - 256)];
        else if (col < 544) v = Wb1[k * 32 + (col - 512)];
        else if (col < 576) v = Wv1[k * 32 + (col - 544)];
        unsigned short h, l; splitbf(v, h, l);
        ws[OFF_WCAT_H + i] = h; ws[OFF_WCAT_L + i] = l;
    }
    for (int i = tid0; i < 256 * 256; i += stride) {
        const int col = i >> 8, k = i & 255;
        unsigned short h, l; splitbf(W1b[k * 256 + col], h, l);
        ws[OFF_W1B_H + i] = h; ws[OFF_W1B_L + i] = l;
    }
    for (int i = tid0; i < 32 * 256; i += stride) {
        const int col = i >> 8, k = i & 255;
        unsigned short h, l; splitbf(Wfb[k * 32 + col], h, l);
        ws[OFF_WFB_H + i] = h; ws[OFF_WFB_L + i] = l;
    }
    for (int i = tid0; i < 32 * 64; i += stride) {
        const int col = i >> 6, k = i & 63;
        unsigned short h, l; splitbf(W_tok[k * 32 + col], h, l);
        ws[OFF_TOK_H + i] = h; ws[OFF_TOK_L + i] = l;
    }
    for (int i = tid0; i < 64 * 32; i += stride) {
        const int col = i >> 5, k = i & 31;
        unsigned short h, l; splitbf(W_yfc[k * 64 + col], h, l);
        ws[OFF_YFC_H + i] = h; ws[OFF_YFC_L + i] = l;
    }
}

// ---------------- main fused kernel ----------------
__global__ __launch_bounds__(THREADS, 2) void xmix_mfma(
    const float* __restrict__ agent_qs,
    const float* __restrict__ states,
    const unsigned short* __restrict__ ws,
    const float* __restrict__ b_tok, const float* __restrict__ b_yfc,
    const float* __restrict__ b1a,  const float* __restrict__ b1b,
    const float* __restrict__ bfa,  const float* __restrict__ bfb,
    const float* __restrict__ bb1,  const float* __restrict__ bv1,
    const float* __restrict__ Wv2,  const float* __restrict__ bv2,
    float* __restrict__ out)
{
    // BB phases:
    //  (1) states-split: hi[64][512]bf16 @0 (64KB), lo @65536
    //  (2) y-split: same layout (overwrites states per-wave, in-order safe)
    //  (3) H1-hi @0 (32KB), H1-lo @32768, HF-hi @65536, HF-lo @98304
    //  (4) w1 f32 [64][256] @0 (64KB), wf f32 [64][32] @65536,
    //      hidden @73728, tprod @81920
    __shared__ __align__(16) unsigned char BBs[131072];
    // SM: e-scratch (P1/P2: 2KB/wave) -> b1 f32 [64][32] @0, v1 @8192
    __shared__ __align__(16) unsigned char SMs[16384];

    const int tid = threadIdx.x;
    const int wv = tid >> 6;          // wave 0..7
    const int l   = tid & 63;
    const int l16 = l & 15;           // MFMA idx16 (row of A / col of B / col of C)
    const int lq  = l >> 4;           // k-group
    const int base = blockIdx.x * TB;

    const f4 fzero = {0.f, 0.f, 0.f, 0.f};

    // ---- P0: load states tile, split to bf16 hi/lo planes in LDS ----
    {
        const float4* gs = (const float4*)(states + (size_t)base * 512);
        #pragma unroll
        for (int i = 0; i < 16; i++) {
            const int idx4 = tid + THREADS * i;
            const float4 v = gs[idx4];
            const int e0 = idx4 * 4;
            const int s = e0 >> 9, c = e0 & 511;
            unsigned short h0, h1, h2, h3, q0, q1, q2, q3;
            splitbf(v.x, h0, q0); splitbf(v.y, h1, q1);
            splitbf(v.z, h2, q2); splitbf(v.w, h3, q3);
            const unsigned sa = swY((unsigned)(s * 1024 + c * 2));
            uint2 uh, ul;
            uh.x = (unsigned)h0 | ((unsigned)h1 << 16);
            uh.y = (unsigned)h2 | ((unsigned)h3 << 16);
            ul.x = (unsigned)q0 | ((unsigned)q1 << 16);
            ul.y = (unsigned)q2 | ((unsigned)q3 << 16);
            *(uint2*)(&BBs[sa])         = uh;
            *(uint2*)(&BBs[65536 + sa]) = ul;
        }
    }
    __syncthreads();

    // ---- P1+P2: e = relu(s@W_tok+b) ; y = relu(e@W_yfc+b) -> Y-split over BB ----
    // wave wv owns e-row-tiles 4wv..4wv+3 (= samples 8wv..8wv+7); in-place safe.
    {
        const unsigned short* tokH = ws + OFF_TOK_H;
        const unsigned short* tokL = ws + OFF_TOK_L;
        const unsigned short* yfcH = ws + OFF_YFC_H;
        const unsigned short* yfcL = ws + OFF_YFC_L;
        unsigned char* scr = &SMs[wv * 2048];   // hi[16][32] @0, lo @1024

        float btok[2];
        btok[0] = b_tok[l16]; btok[1] = b_tok[16 + l16];
        float byfc[4];
        #pragma unroll
        for (int n = 0; n < 4; n++) byfc[n] = b_yfc[n * 16 + l16];

        sh8 TBh[2][2], TBl[2][2];
        #pragma unroll
        for (int n = 0; n < 2; n++)
            #pragma unroll
            for (int kc = 0; kc < 2; kc++) {
                const int coff = (n * 16 + l16) * 64 + kc * 32 + lq * 8;
                TBh[n][kc] = *(const sh8*)(tokH + coff);
                TBl[n][kc] = *(const sh8*)(tokL + coff);
            }
        sh8 YBh[4], YBl[4];
        #pragma unroll
        for (int n = 0; n < 4; n++) {
            const int coff = (n * 16 + l16) * 32 + lq * 8;
            YBh[n] = *(const sh8*)(yfcH + coff);
            YBl[n] = *(const sh8*)(yfcL + coff);
        }

        #pragma unroll
        for (int i = 0; i < 4; i++) {
            const int rt = wv * 4 + i;                 // e-row tile
            const int r = rt * 16 + l16;               // this lane's A-row
            const int s = r >> 3, a = r & 7;
            f4 eacc[2] = {fzero, fzero};
            #pragma unroll
            for (int kc = 0; kc < 2; kc++) {
                const unsigned ad = (unsigned)(s * 1024 + (a * 64 + kc * 32 + lq * 8) * 2);
                const unsigned sa = swY(ad);
                const sh8 Ah = *(const sh8*)(&BBs[sa]);
                const sh8 Al = *(const sh8*)(&BBs[65536 + sa]);
                #pragma unroll
                for (int n = 0; n < 2; n++) {
                    eacc[n] = mfma(Ah, TBh[n][kc], eacc[n]);
                    eacc[n] = mfma(Ah, TBl[n][kc], eacc[n]);
                    eacc[n] = mfma(Al, TBh[n][kc], eacc[n]);
                }
            }
            // e -> per-wave scratch (split, swizzled)
            #pragma unroll
            for (int n = 0; n < 2; n++)
                #pragma unroll
                for (int j = 0; j < 4; j++) {
                    const float e = fmaxf(eacc[n][j] + btok[n], 0.f);
                    const int rr = lq * 4 + j, cc = n * 16 + l16;
                    const unsigned sa = swS((unsigned)(rr * 64 + cc * 2));
                    unsigned short hh, ll; splitbf(e, hh, ll);
                    *(unsigned short*)(scr + sa)        = hh;
                    *(unsigned short*)(scr + 1024 + sa) = ll;
                }
            // P2: y-tile = e-tile @ W_yfc
            f4 yacc[4] = {fzero, fzero, fzero, fzero};
            {
                const unsigned sa = swS((unsigned)(l16 * 64 + lq * 16));
                const sh8 Ah = *(const sh8*)(scr + sa);
                const sh8 Al = *(const sh8*)(scr + 1024 + sa);
                #pragma unroll
                for (int n = 0; n < 4; n++) {
                    yacc[n] = mfma(Ah, YBh[n], yacc[n]);
                    yacc[n] = mfma(Ah, YBl[n], yacc[n]);
                    yacc[n] = mfma(Al, YBh[n], yacc[n]);
                }
            }
            // y -> Y-split (overwrite this wave's samples' states rows)
            #pragma unroll
            for (int n = 0; n < 4; n++)
                #pragma unroll
                for (int j = 0; j < 4; j++) {
                    const float y = fmaxf(yacc[n][j] + byfc[n], 0.f);
                    const int rr = rt * 16 + lq * 4 + j;
                    const int ss = rr >> 3, aa = rr & 7, ff = n * 16 + l16;
                    const unsigned sa = swY((unsigned)(ss * 1024 + (aa * 64 + ff) * 2));
                    unsigned short hh, ll; splitbf(y, hh, ll);
                    *(unsigned short*)(&BBs[sa])         = hh;
                    *(unsigned short*)(&BBs[65536 + sa]) = ll;
                }
        }
    }
    __syncthreads();

    // ---- P3: Y[64,512] @ Wcat[512,640] -> H1|HF|b1|v1 (wave wv: N-tiles 5wv..5wv+4) ----
    f4 acc3[4][5];
    #pragma unroll
    for (int m = 0; m < 4; m++)
        #pragma unroll
        for (int t = 0; t < 5; t++) acc3[m][t] = fzero;
    {
        const unsigned short* wcH = ws + OFF_WCAT_H;
        const unsigned short* wcL = ws + OFF_WCAT_L;
        int cb[5];
        #pragma unroll
        for (int t = 0; t < 5; t++) cb[t] = ((wv * 5 + t) * 16 + l16) * 512;
        int rowb[4];
        #pragma unroll
        for (int m = 0; m < 4; m++) rowb[m] = (m * 16 + l16) * 1024;

        sh8 BhA[5], BlA[5], BhB[5], BlB[5];

#define LOADB(BH, BL, KC) { \
        const int ko_ = (KC) * 32 + lq * 8; \
        _Pragma("unroll") \
        for (int t = 0; t < 5; t++) { \
            BH[t] = *(const sh8*)(wcH + cb[t] + ko_); \
            BL[t] = *(const sh8*)(wcL + cb[t] + ko_); \
        } }

#define DOMFMA(BH, BL, KC) { \
        const int ko_ = (KC) * 32 + lq * 8; \
        sh8 Ah_[4], Al_[4]; \
        _Pragma("unroll") \
        for (int m = 0; m < 4; m++) { \
            const unsigned sa_ = swY((unsigned)(rowb[m] + ko_ * 2)); \
            Ah_[m] = *(const sh8*)(&BBs[sa_]); \
            Al_[m] = *(const sh8*)(&BBs[65536 + sa_]); \
        } \
        _Pragma("unroll") \
        for (int m = 0; m < 4; m++) \
            _Pragma("unroll") \
            for (int t = 0; t < 5; t++) acc3[m][t] = mfma(Ah_[m], BH[t], acc3[m][t]); \
        _Pragma("unroll") \
        for (int m = 0; m < 4; m++) \
            _Pragma("unroll") \
            for (int t = 0; t < 5; t++) acc3[m][t] = mfma(Ah_[m], BL[t], acc3[m][t]); \
        _Pragma("unroll") \
        for (int m = 0; m < 4; m++) \
            _Pragma("unroll") \
            for (int t = 0; t < 5; t++) acc3[m][t] = mfma(Al_[m], BH[t], acc3[m][t]); \
        }

        LOADB(BhA, BlA, 0);
        #pragma unroll 1
        for (int kc2 = 0; kc2 < 8; kc2++) {
            LOADB(BhB, BlB, kc2 * 2 + 1);
            DOMFMA(BhA, BlA, kc2 * 2);
            LOADB(BhA, BlA, kc2 * 2 + 2);   // kc=16 prefetch reads in-bounds garbage, unused
            DOMFMA(BhB, BlB, kc2 * 2 + 1);
        }
#undef LOADB
#undef DOMFMA
    }
    __syncthreads();   // all waves done reading Y

    // ---- P3 epilogue: acc3 -> H1-split / HF-split / b1 / v1 ----
    {
        #pragma unroll
        for (int t = 0; t < 5; t++) {
            const int gt = wv * 5 + t;
            const int cg = gt * 16 + l16;
            if (gt < 16) {                       // H1 = relu(y@W1a + b1a), split
                const float bias = b1a[cg];
                #pragma unroll
                for (int m = 0; m < 4; m++)
                    #pragma unroll
                    for (int j = 0; j < 4; j++) {
                        const int row = m * 16 + lq * 4 + j;
                        const float h = fmaxf(acc3[m][t][j] + bias, 0.f);
                        unsigned short hh, ll; splitbf(h, hh, ll);
                        const unsigned sa = swH((unsigned)(row * 512 + cg * 2));
                        *(unsigned short*)(&BBs[sa])         = hh;
                        *(unsigned short*)(&BBs[32768 + sa]) = ll;
                    }
            } else if (gt < 32) {                // HF = relu(y@Wfa + bfa), split
                const int c = cg - 256;
                const float bias = bfa[c];
                #pragma unroll
                for (int m = 0; m < 4; m++)
                    #pragma unroll
                    for (int j = 0; j < 4; j++) {
                        const int row = m * 16 + lq * 4 + j;
                        const float h = fmaxf(acc3[m][t][j] + bias, 0.f);
                        unsigned short hh, ll; splitbf(h, hh, ll);
                        const unsigned sa = swH((unsigned)(row * 512 + c * 2));
                        *(unsigned short*)(&BBs[65536 + sa]) = hh;
                        *(unsigned short*)(&BBs[98304 + sa]) = ll;
                    }
            } else if (gt < 34) {                // b1 = y@Wb1 + bb1 (no relu), f32
                const int c = cg - 512;
                const float bias = bb1[c];
                #pragma unroll
                for (int m = 0; m < 4; m++)
                    #pragma unroll
                    for (int j = 0; j < 4; j++) {
                        const int row = m * 16 + lq * 4 + j;
                        *(float*)(&SMs[(row * 32 + c) * 4]) = acc3[m][t][j] + bias;
                    }
            } else if (gt < 36) {                // v1 = relu(y@Wv1 + bv1), f32
                const int c = cg - 544;
                const float bias = bv1[c];
                #pragma unroll
                for (int m = 0; m < 4; m++)
                    #pragma unroll
                    for (int j = 0; j < 4; j++) {
                        const int row = m * 16 + lq * 4 + j;
                        *(float*)(&SMs[8192 + (row * 32 + c) * 4]) =
                            fmaxf(acc3[m][t][j] + bias, 0.f);
                    }
            } // gt>=36: pad, discard
        }
    }
    __syncthreads();

    // ---- P4: w1 = |H1@W1b + b1b| ; wf = |HF@Wfb + bfb| ----
    f4 acc4[4][2];
    #pragma unroll
    for (int m = 0; m < 4; m++) { acc4[m][0] = fzero; acc4[m][1] = fzero; }
    f4 accw = fzero;
    {
        const unsigned short* w1H = ws + OFF_W1B_H;
        const unsigned short* w1L = ws + OFF_W1B_L;
        const unsigned short* wfH = ws + OFF_WFB_H;
        const unsigned short* wfL = ws + OFF_WFB_L;
        const int mw = wv & 3, nw = wv >> 2;     // this wave's wf (M,N) pair
        const int cb0 = ((wv * 2 + 0) * 16 + l16) * 256;
        const int cb1 = ((wv * 2 + 1) * 16 + l16) * 256;
        const int cbw = (nw * 16 + l16) * 256;
        #pragma unroll 2
        for (int kc = 0; kc < 8; kc++) {
            const int ko = kc * 32 + lq * 8;
            const sh8 B0h = *(const sh8*)(w1H + cb0 + ko);
            const sh8 B0l = *(const sh8*)(w1L + cb0 + ko);
            const sh8 B1h = *(const sh8*)(w1H + cb1 + ko);
            const sh8 B1l = *(const sh8*)(w1L + cb1 + ko);
            const sh8 Wh  = *(const sh8*)(wfH + cbw + ko);
            const sh8 Wl  = *(const sh8*)(wfL + cbw + ko);
            sh8 Ah[4], Al[4];
            #pragma unroll
            for (int m = 0; m < 4; m++) {
                const unsigned sa = swH((unsigned)((m * 16 + l16) * 512 + ko * 2));
                Ah[m] = *(const sh8*)(&BBs[sa]);
                Al[m] = *(const sh8*)(&BBs[32768 + sa]);
            }
            const unsigned saw = swH((unsigned)((mw * 16 + l16) * 512 + ko * 2));
            const sh8 Awh = *(const sh8*)(&BBs[65536 + saw]);
            const sh8 Awl = *(const sh8*)(&BBs[98304 + saw]);
            #pragma unroll
            for (int m = 0; m < 4; m++) {
                acc4[m][0] = mfma(Ah[m], B0h, acc4[m][0]);
                acc4[m][1] = mfma(Ah[m], B1h, acc4[m][1]);
            }
            accw = mfma(Awh, Wh, accw);
            #pragma unroll
            for (int m = 0; m < 4; m++) {
                acc4[m][0] = mfma(Ah[m], B0l, acc4[m][0]);
                acc4[m][1] = mfma(Ah[m], B1l, acc4[m][1]);
            }
            accw = mfma(Awh, Wl, accw);
            #pragma unroll
            for (int m = 0; m < 4; m++) {
                acc4[m][0] = mfma(Al[m], B0h, acc4[m][0]);
                acc4[m][1] = mfma(Al[m], B1h, acc4[m][1]);
            }
            accw = mfma(Awl, Wh, accw);
        }
    }
    __syncthreads();   // H1/HF consumed

    // w1/wf -> f32 LDS
    {
        #pragma unroll
        for (int t = 0; t < 2; t++) {
            const int col = (wv * 2 + t) * 16 + l16;
            const float bias = b1b[col];
            #pragma unroll
            for (int m = 0; m < 4; m++)
                #pragma unroll
                for (int j = 0; j < 4; j++) {
                    const int row = m * 16 + lq * 4 + j;
                    *(float*)(&BBs[(row * 256 + col) * 4]) =
                        fabsf(acc4[m][t][j] + bias);
                }
        }
        {
            const int col = (wv >> 2) * 16 + l16;
            const float bias = bfb[col];
            const int m = wv & 3;
            #pragma unroll
            for (int j = 0; j < 4; j++) {
                const int row = m * 16 + lq * 4 + j;
                *(float*)(&BBs[65536 + (row * 32 + col) * 4]) =
                    fabsf(accw[j] + bias);
            }
        }
    }
    __syncthreads();

    // ---- P5: epilogue (elu, delu, q_tot, grad) ----
    {
        const int s = tid >> 3, li = tid & 7;
        const int b = base + s;
        float q[8];
        #pragma unroll
        for (int a = 0; a < 8; a++) q[a] = agent_qs[(size_t)b * 8 + a];
        const float* w1p = (const float*)(&BBs[0]);        // [64][256]
        const float* wfp = (const float*)(&BBs[65536]);    // [64][32]
        const float* b1p = (const float*)(&SMs[0]);        // [64][32]
        float* hidp = (float*)(&BBs[73728]);
        float* tpp  = (float*)(&BBs[81920]);
        #pragma unroll
        for (int i = 0; i < 4; i++) {
            const int e = li + 8 * i;
            float z = b1p[s * 32 + e];
            #pragma unroll
            for (int a = 0; a < 8; a++) z = fmaf(q[a], w1p[s * 256 + a * 32 + e], z);
            const float h = (z > 0.f) ? z : (expf(z) - 1.f);   // elu
            const float d = (h < 0.f) ? expf(h) : 1.f;          // delu of elu OUTPUT (ref!)
            hidp[s * 32 + e] = h;
            tpp[s * 32 + e] = d * wfp[s * 32 + e];
        }
    }
    __syncthreads();
    {
        const float* w1p = (const float*)(&BBs[0]);
        const float* wfp = (const float*)(&BBs[65536]);
        const float* v1p = (const float*)(&SMs[8192]);
        const float* hidp = (const float*)(&BBs[73728]);
        const float* tpp  = (const float*)(&BBs[81920]);
        const int s = tid >> 3, a = tid & 7;
        const int b = base + s;
        float g = 0.f;
        #pragma unroll
        for (int e = 0; e < 32; e++)
            g = fmaf(w1p[s * 256 + a * 32 + e], tpp[s * 32 + e], g);
        out[NB + (size_t)b * 8 + a] = g;
        if (tid < 64) {
            const int s2 = tid, b2 = base + s2;
            float v = bv2[0];
            #pragma unroll
            for (int e = 0; e < 32; e++) v = fmaf(v1p[s2 * 32 + e], Wv2[e], v);
            float qt = v;
            #pragma unroll
            for (int e = 0; e < 32; e++)
                qt = fmaf(hidp[s2 * 32 + e], wfp[s2 * 32 + e], qt);
            out[b2] = qt;
        }
    }
}

extern "C" void kernel_launch(void* const* d_in, const int* in_sizes, int n_in,
                              void* d_out, int out_size, void* d_ws, size_t ws_size,
                              hipStream_t stream) {
    const float* agent_qs = (const float*)d_in[0];
    // d_in[1] = hist (unused by reference)
    const float* states   = (const float*)d_in[2];
    // d_in[3] = obs (unused by reference)
    const float* W_tok = (const float*)d_in[4];
    const float* b_tok = (const float*)d_in[5];
    const float* W_yfc = (const float*)d_in[6];
    const float* b_yfc = (const float*)d_in[7];
    const float* W1a   = (const float*)d_in[8];
    const float* b1a   = (const float*)d_in[9];
    const float* W1b   = (const float*)d_in[10];
    const float* b1b   = (const float*)d_in[11];
    const float* Wfa   = (const float*)d_in[12];
    const float* bfa   = (const float*)d_in[13];
    const float* Wfb   = (const float*)d_in[14];
    const float* bfb   = (const float*)d_in[15];
    const float* Wb1   = (const float*)d_in[16];
    const float* bb1   = (const float*)d_in[17];
    const float* Wv1   = (const float*)d_in[18];
    const float* bv1   = (const float*)d_in[19];
    const float* Wv2   = (const float*)d_in[20];
    const float* bv2   = (const float*)d_in[21];
    float* out = (float*)d_out;
    unsigned short* ws = (unsigned short*)d_ws;   // needs 1,622,016 B

    xmix_prep<<<512, 256, 0, stream>>>(W_tok, W_yfc, W1a, W1b, Wfa, Wfb, Wb1, Wv1, ws);
    xmix_mfma<<<NBLOCKS, THREADS, 0, stream>>>(
        agent_qs, states, ws, b_tok, b_yfc, b1a, b1b, bfa, bfb,
        bb1, bv1, Wv2, bv2, out);
}